// Round 6
// baseline (872.290 us; speedup 1.0000x reference)
//
#include <hip/hip_runtime.h>
#include <hip/hip_bf16.h>
#include <stdint.h>

// BitNet MNIST MLP, Round 5: 256x256 4-phase GEMM with register-double-buffered
// fragments read ONE PHASE AHEAD (MFMA-then-read phase bodies) so the LDS pipe
// services next-phase reads while the MFMA pipe crunches. 4 barriers/K-tile
// (was 8), 24 ds_read/wave/K-tile (was 28). vmcnt(6) fence @P3, st_16x32
// swizzle, setprio, XCD-grouped grid.

typedef __attribute__((ext_vector_type(8))) short short8;
typedef __attribute__((ext_vector_type(4))) float f32x4;

#define B_TOTAL 65536
#define IN_DIM 784
#define IN_PAD 896
#define H_DIM 1024
#define OUT_DIM 10
#define OUT_PAD 16

__device__ __forceinline__ unsigned short f2bf(float f) {
    union { float f; unsigned u; } c; c.f = f;
    unsigned r = c.u + 0x7FFFu + ((c.u >> 16) & 1u);
    return (unsigned short)(r >> 16);
}
__device__ __forceinline__ float bf2f(unsigned short h) {
    union { unsigned u; float f; } c; c.u = ((unsigned)h) << 16;
    return c.f;
}

#define GLOAD16(gp, lp)                                                        \
    __builtin_amdgcn_global_load_lds(                                          \
        (const __attribute__((address_space(1))) void*)(gp),                   \
        (__attribute__((address_space(3))) void*)(lp), 16, 0, 0)

#define BAR()                                                                  \
    {   __builtin_amdgcn_sched_barrier(0);                                     \
        __builtin_amdgcn_s_barrier();                                          \
        __builtin_amdgcn_sched_barrier(0); }

// ---------- weight |w| sum (double atomic: deterministic) ----------
__global__ void absum_kernel(const float* __restrict__ w, int n, double* acc) {
    __shared__ float red[4];
    float s = 0.f;
    for (int i = blockIdx.x * blockDim.x + threadIdx.x; i < n; i += gridDim.x * blockDim.x)
        s += fabsf(w[i]);
#pragma unroll
    for (int o = 32; o > 0; o >>= 1) s += __shfl_xor(s, o);
    if ((threadIdx.x & 63) == 0) red[threadIdx.x >> 6] = s;
    __syncthreads();
    if (threadIdx.x == 0) {
        float t = red[0] + red[1] + red[2] + red[3];
        atomicAdd(acc, (double)t);
    }
}

// ---------- ternary quantize -> bf16, pad K to Kp and O rows up ----------
__global__ void quant_kernel(const float* __restrict__ w, unsigned short* __restrict__ wq,
                             int O, int K, int Kp, const double* sum, int n) {
    int k = blockIdx.x * blockDim.x + threadIdx.x;
    int o = blockIdx.y;
    if (k >= Kp) return;
    float scale = fmaxf((float)(*sum / (double)n), 1e-5f);
    float q = 0.f;
    if (o < O && k < K) {
        float r = rintf(w[(size_t)o * K + k] / scale);  // round-half-even == jnp.round
        q = fminf(1.f, fmaxf(-1.f, r));
    }
    wq[(size_t)o * Kp + k] = f2bf(q);
}

// ---------- x fp32 [R x 784] -> bf16 [R x 896] (zero-padded) ----------
__global__ __launch_bounds__(256)
void convert_pad(const float* __restrict__ x, unsigned short* __restrict__ xb) {
    const int g = blockIdx.x * 256 + threadIdx.x;   // one 8-col group per thread
    const int row = g / 112;
    const int c = (g % 112) * 8;
    short8 v = 0;
    if (c < IN_DIM) {
        const float* p = x + (size_t)row * IN_DIM + c;
        float4 f0 = *(const float4*)p;
        float4 f1 = *(const float4*)(p + 4);
        v[0] = (short)f2bf(f0.x); v[1] = (short)f2bf(f0.y);
        v[2] = (short)f2bf(f0.z); v[3] = (short)f2bf(f0.w);
        v[4] = (short)f2bf(f1.x); v[5] = (short)f2bf(f1.y);
        v[6] = (short)f2bf(f1.z); v[7] = (short)f2bf(f1.w);
    }
    *(short8*)(xb + (size_t)row * IN_PAD + c) = v;
}

// ---------- GEMM: C[M x 1024] = A[M x KP] * Bq[1024 x KP]^T ----------
// 256x256 tile, 8 waves (2m x 4n), BK=64, 2 K-tile LDS ring, st_16x32 swizzle.
// Fragment flow (reads issued AFTER the MFMA cluster of the same phase):
//   P1(t): MFMA Q(0,0)[afQ0,bf0]; read B-nq1(t)->bf1;  stage A-g0(t+2),B-nq0(t+2)->cur
//   P2(t): MFMA Q(0,1)[afQ0,bf1]; read A-g1(t)->afQ1;  stage B-nq1(t+2)->cur
//   P3(t): MFMA Q(1,1)[afQ1,bf1]; read A-g0(t+1)->afQ0; stage A-g1(t+2)->cur
//          [fence vmcnt(6) before BAR: prev iter's 8 stage-loads drained]
//   P4(t): MFMA Q(1,0)[afQ1,bf0]; read B-nq0(t+1)->bf0
// LDS slot safety: each stage target's last ds_read was drained by the
// lgkmcnt(0)-before-barrier of an earlier phase (verified per group).
template<int KP>
__global__ __launch_bounds__(512, 2)
void gemm_bt(const unsigned short* __restrict__ A, const unsigned short* __restrict__ Bq,
             unsigned short* __restrict__ C) {
    constexpr int NT = KP / 64;
    __shared__ __attribute__((aligned(16))) unsigned short LDS[65536];  // 128 KB
    const int tid = threadIdx.x;
    const int lane = tid & 63;
    const int w = tid >> 6;
    const int wm = w >> 2, wn = w & 3;
    const int lr = lane & 15, gq = lane >> 4;
    const int gsw8 = (gq ^ ((lr >> 3) << 1)) * 8;   // swizzled granule offset (shorts)
    const int lrO = lr * 32;
    // XCD-grouped bijective swizzle (grid = Mblks*4, Mblks % 8 == 0)
    const int bid = blockIdx.x;
    const int xcd = bid & 7, slot = bid >> 3;
    const int nblk = slot & 3;
    const int mblk = xcd * (gridDim.x >> 5) + (slot >> 2);
    const int m0 = mblk * 256, n0 = nblk * 256;
    // staging source coords (pre-swizzled involution)
    const int rS = lane >> 2;                              // row within 16-row subtile
    const int cS = ((lane & 3) ^ ((lane >> 5) << 1)) * 8;  // swizzled col granule
    // per-wave slot assignments (wave w stages slots st and st+16 of a group)
    const int stA0 = w;                          // A-g0: read by LD Q-group 0
    const int stA1 = 8 + w;                      // A-g1: read by LD Q-group 1
    const int stB_P1 = (w >> 2) * 8 + (w & 3);   // B-nq0
    const int stB_P3 = stB_P1 + 4;               // B-nq1

#define STG(gbase, areaS, st)                                                  \
    {   const unsigned short* _g = (gbase) +                                   \
            (size_t)(((st) >> 1) * 16 + rS) * KP + ((st) & 1) * 32 + cS;       \
        GLOAD16(_g, &LDS[(areaS) + (st) * 512]);                               \
        GLOAD16(_g + (size_t)128 * KP, &LDS[(areaS) + (st) * 512 + 8192]); }
#define ABASE(t) (A + (size_t)m0 * KP + (t) * 64)
#define BBASE(t) (Bq + (size_t)n0 * KP + (t) * 64)
#define LD_A_TO(dst, mq, areaS)                                                \
    _Pragma("unroll") for (int mf = 0; mf < 4; ++mf)                           \
    _Pragma("unroll") for (int kk = 0; kk < 2; ++kk)                           \
        dst[mf][kk] = *(const short8*)&LDS[(areaS) +                           \
            ((wm * 8 + (mq) * 4 + mf) * 2 + kk) * 512 + lrO + gsw8];
#define LD_B_TO(dst, nq, areaS)                                                \
    _Pragma("unroll") for (int nf = 0; nf < 2; ++nf)                           \
    _Pragma("unroll") for (int kk = 0; kk < 2; ++kk)                           \
        dst[nf][kk] = *(const short8*)&LDS[(areaS) + 16384 +                   \
            ((wn * 4 + (nq) * 2 + nf) * 2 + kk) * 512 + lrO + gsw8];
#define QMM(mq, nq, Af, Bf)                                                    \
    _Pragma("unroll") for (int kk = 0; kk < 2; ++kk)                           \
    _Pragma("unroll") for (int mf = 0; mf < 4; ++mf)                           \
    _Pragma("unroll") for (int nf = 0; nf < 2; ++nf)                           \
        acc[(mq) * 4 + mf][(nq) * 2 + nf] =                                    \
            __builtin_amdgcn_mfma_f32_16x16x32_bf16(Af[mf][kk], Bf[nf][kk],    \
                acc[(mq) * 4 + mf][(nq) * 2 + nf], 0, 0, 0);

    f32x4 acc[8][4] = {};
    short8 afQ0[4][2], afQ1[4][2], bf0[2][2], bf1[2][2];
    // prologue: tile0 (8 loads) then tile1 (8 loads); drain tile0; pre-read P1(0)
    STG(ABASE(0), 0, stA0);
    STG(BBASE(0), 16384, stB_P1);
    STG(BBASE(0), 16384, stB_P3);
    STG(ABASE(0), 0, stA1);
    STG(ABASE(1), 32768, stA0);
    STG(BBASE(1), 49152, stB_P1);
    STG(BBASE(1), 49152, stB_P3);
    STG(ABASE(1), 32768, stA1);
    __builtin_amdgcn_sched_barrier(0);
    asm volatile("s_waitcnt vmcnt(8)" ::: "memory");   // tile0 landed
    BAR();
    LD_A_TO(afQ0, 0, 0);
    LD_B_TO(bf0, 0, 0);
#pragma unroll 2
    for (int t = 0; t < NT; ++t) {
        const int curS = (t & 1) * 32768;
        const int nxtS = curS ^ 32768;
        // ---- P1: Q(0,0) ----
        __builtin_amdgcn_sched_barrier(0);
        asm volatile("s_waitcnt lgkmcnt(0)" ::: "memory");
        BAR();
        __builtin_amdgcn_s_setprio(1); QMM(0, 0, afQ0, bf0); __builtin_amdgcn_s_setprio(0);
        __builtin_amdgcn_sched_barrier(0);
        LD_B_TO(bf1, 1, curS);
        if (t + 2 < NT) {
            STG(ABASE(t + 2), curS, stA0);
            STG(BBASE(t + 2), curS + 16384, stB_P1);
        }
        // ---- P2: Q(0,1) ----
        __builtin_amdgcn_sched_barrier(0);
        asm volatile("s_waitcnt lgkmcnt(0)" ::: "memory");
        BAR();
        __builtin_amdgcn_s_setprio(1); QMM(0, 1, afQ0, bf1); __builtin_amdgcn_s_setprio(0);
        __builtin_amdgcn_sched_barrier(0);
        LD_A_TO(afQ1, 1, curS);
        if (t + 2 < NT) STG(BBASE(t + 2), curS + 16384, stB_P3);
        // ---- P3: Q(1,1) ---- (fence: prev iter's stages = tile t+1 landed)
        __builtin_amdgcn_sched_barrier(0);
        asm volatile("s_waitcnt lgkmcnt(0)" ::: "memory");
        if (t + 2 < NT) { asm volatile("s_waitcnt vmcnt(6)" ::: "memory"); }
        else            { asm volatile("s_waitcnt vmcnt(0)" ::: "memory"); }
        BAR();
        __builtin_amdgcn_s_setprio(1); QMM(1, 1, afQ1, bf1); __builtin_amdgcn_s_setprio(0);
        __builtin_amdgcn_sched_barrier(0);
        if (t + 1 < NT) LD_A_TO(afQ0, 0, nxtS);
        if (t + 2 < NT) STG(ABASE(t + 2), curS, stA1);
        // ---- P4: Q(1,0) ----
        __builtin_amdgcn_sched_barrier(0);
        asm volatile("s_waitcnt lgkmcnt(0)" ::: "memory");
        BAR();
        __builtin_amdgcn_s_setprio(1); QMM(1, 0, afQ1, bf0); __builtin_amdgcn_s_setprio(0);
        __builtin_amdgcn_sched_barrier(0);
        if (t + 1 < NT) LD_B_TO(bf0, 0, nxtS);
    }
    // epilogue: C/D layout col=lane&15, row=(lane>>4)*4+j (HW-verified)
#pragma unroll
    for (int mf = 0; mf < 8; ++mf) {
        const int grow = m0 + wm * 128 + mf * 16 + (lane >> 4) * 4;
#pragma unroll
        for (int nf = 0; nf < 4; ++nf) {
            const int gcol = n0 + wn * 64 + nf * 16 + lr;
            unsigned short* Cp = C + (size_t)grow * H_DIM + gcol;
#pragma unroll
            for (int j = 0; j < 4; ++j) Cp[(size_t)j * H_DIM] = f2bf(acc[mf][nf][j]);
        }
    }
#undef STG
#undef ABASE
#undef BBASE
#undef LD_A_TO
#undef LD_B_TO
#undef QMM
}

// ---------- rmsnorm + exact gelu, one wave per 1024-wide row ----------
__global__ __launch_bounds__(256)
void norm_gelu(const unsigned short* __restrict__ Hp, const float* __restrict__ g,
               unsigned short* __restrict__ U) {
    const int row = blockIdx.x * 4 + (threadIdx.x >> 6);
    const int lane = threadIdx.x & 63;
    const unsigned short* rp = Hp + (size_t)row * H_DIM;
    short8 v0 = *(const short8*)(rp + lane * 8);
    short8 v1 = *(const short8*)(rp + 512 + lane * 8);
    float f[16];
#pragma unroll
    for (int j = 0; j < 8; ++j) {
        f[j] = bf2f((unsigned short)v0[j]);
        f[8 + j] = bf2f((unsigned short)v1[j]);
    }
    float s = 0.f;
#pragma unroll
    for (int j = 0; j < 16; ++j) s += f[j] * f[j];
#pragma unroll
    for (int o = 32; o > 0; o >>= 1) s += __shfl_xor(s, o);
    const float rinv = 1.f / sqrtf(s * (1.f / 1024.f) + 1e-6f);
    short8 o0, o1;
#pragma unroll
    for (int j = 0; j < 8; ++j) {
        const int c0 = lane * 8 + j, c1 = 512 + lane * 8 + j;
        float t0 = f[j] * rinv * g[c0];
        float t1 = f[8 + j] * rinv * g[c1];
        float u0 = 0.5f * t0 * (1.f + erff(t0 * 0.70710678118f));
        float u1 = 0.5f * t1 * (1.f + erff(t1 * 0.70710678118f));
        o0[j] = (short)f2bf(u0);
        o1[j] = (short)f2bf(u1);
    }
    unsigned short* up = U + (size_t)row * H_DIM;
    *(short8*)(up + lane * 8) = o0;
    *(short8*)(up + 512 + lane * 8) = o1;
}

// ---------- final layer: out[M x 10] = A[M x 1024] * w3q[16 x 1024]^T ----------
__global__ __launch_bounds__(256)
void gemm3_kernel(const unsigned short* __restrict__ A, const unsigned short* __restrict__ Bq,
                  float* __restrict__ out) {
    __shared__ unsigned short As[128][40];
    __shared__ unsigned short Bs[16][40];
    const int tid = threadIdx.x;
    const int lane = tid & 63;
    const int wid = tid >> 6;
    const int m0 = blockIdx.x * 128;
    const int lr = lane & 15;
    const int lk = (lane >> 4) * 8;
    const int sr = tid >> 2;
    const int sc = (tid & 3) * 8;
    f32x4 acc[2] = {};
    for (int kt = 0; kt < 32; ++kt) {
        const int kb = kt * 32;
        __syncthreads();
#pragma unroll
        for (int p = 0; p < 2; ++p) {
            const int r = p * 64 + sr;
            *(short8*)&As[r][sc] = *(const short8*)(A + (size_t)(m0 + r) * H_DIM + kb + sc);
        }
        if (tid < 64) {
            const int r = tid >> 2;
            const int c = (tid & 3) * 8;
            *(short8*)&Bs[r][c] = *(const short8*)(Bq + (size_t)r * H_DIM + kb + c);
        }
        __syncthreads();
        short8 bv = *(const short8*)&Bs[lr][lk];
#pragma unroll
        for (int m = 0; m < 2; ++m) {
            short8 a = *(const short8*)&As[wid * 32 + m * 16 + lr][lk];
            acc[m] = __builtin_amdgcn_mfma_f32_16x16x32_bf16(a, bv, acc[m], 0, 0, 0);
        }
    }
    if (lr < OUT_DIM) {
#pragma unroll
        for (int m = 0; m < 2; ++m)
#pragma unroll
            for (int j = 0; j < 4; ++j) {
                const int grow = m0 + wid * 32 + m * 16 + (lane >> 4) * 4 + j;
                out[(size_t)grow * OUT_DIM + lr] = acc[m][j];
            }
    }
}

extern "C" void kernel_launch(void* const* d_in, const int* in_sizes, int n_in,
                              void* d_out, int out_size, void* d_ws, size_t ws_size,
                              hipStream_t stream) {
    (void)in_sizes; (void)n_in; (void)out_size;
    const float* x  = (const float*)d_in[0];
    const float* w1 = (const float*)d_in[1];
    const float* g1 = (const float*)d_in[2];
    const float* w2 = (const float*)d_in[3];
    const float* g2 = (const float*)d_in[4];
    const float* w3 = (const float*)d_in[5];
    float* out = (float*)d_out;

    uint8_t* ws = (uint8_t*)d_ws;
    double* sums = (double*)ws;
    size_t off = 256;
    unsigned short* w1q = (unsigned short*)(ws + off); off += (size_t)H_DIM * IN_PAD * 2;
    unsigned short* w2q = (unsigned short*)(ws + off); off += (size_t)H_DIM * H_DIM * 2;
    unsigned short* w3q = (unsigned short*)(ws + off); off += (size_t)OUT_PAD * H_DIM * 2;

    // largest pow2 chunk R (multiple of 2048 for the 256-tile XCD swizzle) whose
    // two bf16 [R x 1024] buffers fit; bufB doubles as the bf16 x-chunk [R x 896]
    size_t rem = (ws_size > off) ? ws_size - off : 0;
    int R = B_TOTAL;
    while (R > 2048 && (size_t)2 * R * H_DIM * 2 > rem) R >>= 1;
    unsigned short* bufA = (unsigned short*)(ws + off);
    unsigned short* bufB = bufA + (size_t)R * H_DIM;

    hipMemsetAsync(sums, 0, 3 * sizeof(double), stream);
    absum_kernel<<<128, 256, 0, stream>>>(w1, H_DIM * IN_DIM, sums + 0);
    absum_kernel<<<128, 256, 0, stream>>>(w2, H_DIM * H_DIM, sums + 1);
    absum_kernel<<<128, 256, 0, stream>>>(w3, OUT_DIM * H_DIM, sums + 2);
    quant_kernel<<<dim3((IN_PAD + 255) / 256, H_DIM), 256, 0, stream>>>(
        w1, w1q, H_DIM, IN_DIM, IN_PAD, sums + 0, H_DIM * IN_DIM);
    quant_kernel<<<dim3((H_DIM + 255) / 256, H_DIM), 256, 0, stream>>>(
        w2, w2q, H_DIM, H_DIM, H_DIM, sums + 1, H_DIM * H_DIM);
    quant_kernel<<<dim3((H_DIM + 255) / 256, OUT_PAD), 256, 0, stream>>>(
        w3, w3q, OUT_DIM, H_DIM, H_DIM, sums + 2, OUT_DIM * H_DIM);

    const int nchunk = B_TOTAL / R;
    for (int c = 0; c < nchunk; ++c) {
        const float* xc = x + (size_t)c * R * IN_DIM;
        convert_pad<<<R * 112 / 256, 256, 0, stream>>>(xc, bufB);
        gemm_bt<IN_PAD><<<(R / 256) * 4, 512, 0, stream>>>(bufB, w1q, bufA);
        norm_gelu<<<R / 4, 256, 0, stream>>>(bufA, g1, bufB);
        gemm_bt<H_DIM><<<(R / 256) * 4, 512, 0, stream>>>(bufB, w2q, bufA);
        norm_gelu<<<R / 4, 256, 0, stream>>>(bufA, g2, bufB);
        gemm3_kernel<<<R / 128, 256, 0, stream>>>(bufB, w3q, out + (size_t)c * R * OUT_DIM);
    }
}

// Round 7
// 626.839 us; speedup vs baseline: 1.3916x; 1.3916x over previous
//
#include <hip/hip_runtime.h>
#include <hip/hip_bf16.h>
#include <stdint.h>

// BitNet MNIST MLP, Round 6: 256x256 4-phase GEMM; each phase is ONE barrier
// region {BAR; ds_reads; setprio MFMA; stage} so the compiler's fine-grained
// lgkmcnt waits overlap LDS reads with MFMA (r4 kept them in separate regions
// -> pipes summed). No sched_barrier pinning (m141). Frag live set unchanged
// (48 VGPR; r5's double-buffering spilled past the 256-reg/wave cap).
// Slot lifetimes + vmcnt(6) ledger identical to verified r4.

typedef __attribute__((ext_vector_type(8))) short short8;
typedef __attribute__((ext_vector_type(4))) float f32x4;

#define B_TOTAL 65536
#define IN_DIM 784
#define IN_PAD 896
#define H_DIM 1024
#define OUT_DIM 10
#define OUT_PAD 16

__device__ __forceinline__ unsigned short f2bf(float f) {
    union { float f; unsigned u; } c; c.f = f;
    unsigned r = c.u + 0x7FFFu + ((c.u >> 16) & 1u);
    return (unsigned short)(r >> 16);
}
__device__ __forceinline__ float bf2f(unsigned short h) {
    union { unsigned u; float f; } c; c.u = ((unsigned)h) << 16;
    return c.f;
}

#define GLOAD16(gp, lp)                                                        \
    __builtin_amdgcn_global_load_lds(                                          \
        (const __attribute__((address_space(1))) void*)(gp),                   \
        (__attribute__((address_space(3))) void*)(lp), 16, 0, 0)

// ---------- weight |w| sum (double atomic: deterministic) ----------
__global__ void absum_kernel(const float* __restrict__ w, int n, double* acc) {
    __shared__ float red[4];
    float s = 0.f;
    for (int i = blockIdx.x * blockDim.x + threadIdx.x; i < n; i += gridDim.x * blockDim.x)
        s += fabsf(w[i]);
#pragma unroll
    for (int o = 32; o > 0; o >>= 1) s += __shfl_xor(s, o);
    if ((threadIdx.x & 63) == 0) red[threadIdx.x >> 6] = s;
    __syncthreads();
    if (threadIdx.x == 0) {
        float t = red[0] + red[1] + red[2] + red[3];
        atomicAdd(acc, (double)t);
    }
}

// ---------- ternary quantize -> bf16, pad K to Kp and O rows up ----------
__global__ void quant_kernel(const float* __restrict__ w, unsigned short* __restrict__ wq,
                             int O, int K, int Kp, const double* sum, int n) {
    int k = blockIdx.x * blockDim.x + threadIdx.x;
    int o = blockIdx.y;
    if (k >= Kp) return;
    float scale = fmaxf((float)(*sum / (double)n), 1e-5f);
    float q = 0.f;
    if (o < O && k < K) {
        float r = rintf(w[(size_t)o * K + k] / scale);  // round-half-even == jnp.round
        q = fminf(1.f, fmaxf(-1.f, r));
    }
    wq[(size_t)o * Kp + k] = f2bf(q);
}

// ---------- x fp32 [R x 784] -> bf16 [R x 896] (zero-padded) ----------
__global__ __launch_bounds__(256)
void convert_pad(const float* __restrict__ x, unsigned short* __restrict__ xb) {
    const int g = blockIdx.x * 256 + threadIdx.x;   // one 8-col group per thread
    const int row = g / 112;
    const int c = (g % 112) * 8;
    short8 v = 0;
    if (c < IN_DIM) {
        const float* p = x + (size_t)row * IN_DIM + c;
        float4 f0 = *(const float4*)p;
        float4 f1 = *(const float4*)(p + 4);
        v[0] = (short)f2bf(f0.x); v[1] = (short)f2bf(f0.y);
        v[2] = (short)f2bf(f0.z); v[3] = (short)f2bf(f0.w);
        v[4] = (short)f2bf(f1.x); v[5] = (short)f2bf(f1.y);
        v[6] = (short)f2bf(f1.z); v[7] = (short)f2bf(f1.w);
    }
    *(short8*)(xb + (size_t)row * IN_PAD + c) = v;
}

// ---------- GEMM: C[M x 1024] = A[M x KP] * Bq[1024 x KP]^T ----------
// 256x256 tile, 8 waves (2m x 4n), BK=64, 2 K-tile LDS ring, st_16x32 swizzle.
// Phase p = {s_barrier; ds_reads(p); setprio(1) 16 MFMA setprio(0); stage}.
// Stage targets are disjoint from the same region's read slots:
//   P1 stages B-nq0(t+1)->NXT (reads hit cur);  P2 stages A-g0(t+2) (reads=B);
//   P3 stages B-nq1(t+2)    (reads=A-g1);       P4 stages A-g1(t+2) (reads=B).
// Previous reader of each target drained (compiler lgkm waits before its MFMA)
// one barrier upstream. Fence vmcnt(6) once per K-tile at P4 end (drains all
// of tile t+1; tile t+2's 3 groups stay in flight); vmcnt(0) at t==NT-2.
template<int KP>
__global__ __launch_bounds__(512, 2)
void gemm_bt(const unsigned short* __restrict__ A, const unsigned short* __restrict__ Bq,
             unsigned short* __restrict__ C) {
    constexpr int NT = KP / 64;
    __shared__ __attribute__((aligned(16))) unsigned short LDS[65536];  // 128 KB
    const int tid = threadIdx.x;
    const int lane = tid & 63;
    const int w = tid >> 6;
    const int wm = w >> 2, wn = w & 3;
    const int lr = lane & 15, gq = lane >> 4;
    const int gsw8 = (gq ^ ((lr >> 3) << 1)) * 8;   // swizzled granule offset (shorts)
    const int lrO = lr * 32;
    // XCD-grouped bijective swizzle (grid = Mblks*4, Mblks % 8 == 0)
    const int bid = blockIdx.x;
    const int xcd = bid & 7, slot = bid >> 3;
    const int nblk = slot & 3;
    const int mblk = xcd * (gridDim.x >> 5) + (slot >> 2);
    const int m0 = mblk * 256, n0 = nblk * 256;
    // staging source coords (pre-swizzled involution)
    const int rS = lane >> 2;                              // row within 16-row subtile
    const int cS = ((lane & 3) ^ ((lane >> 5) << 1)) * 8;  // swizzled col granule
    // per-wave slot assignments (wave w stages slots st and st+16 of a group)
    const int stA0 = w;                          // A-g0: read @P1 (LD_A(0))
    const int stA1 = 8 + w;                      // A-g1: read @P3 (LD_A(1))
    const int stB_P1 = (w >> 2) * 8 + (w & 3);   // B-nq0: read @P1,P4 (LD_B(0))
    const int stB_P3 = stB_P1 + 4;               // B-nq1: read @P2 (LD_B(1))

#define STG(gbase, areaS, st)                                                  \
    {   const unsigned short* _g = (gbase) +                                   \
            (size_t)(((st) >> 1) * 16 + rS) * KP + ((st) & 1) * 32 + cS;       \
        GLOAD16(_g, &LDS[(areaS) + (st) * 512]);                               \
        GLOAD16(_g + (size_t)128 * KP, &LDS[(areaS) + (st) * 512 + 8192]); }
#define ABASE(t) (A + (size_t)m0 * KP + (t) * 64)
#define BBASE(t) (Bq + (size_t)n0 * KP + (t) * 64)
#define LD_A(mq)                                                               \
    _Pragma("unroll") for (int mf = 0; mf < 4; ++mf)                           \
    _Pragma("unroll") for (int kk = 0; kk < 2; ++kk)                           \
        af[mf][kk] = *(const short8*)&LDS[curS +                               \
            ((wm * 8 + (mq) * 4 + mf) * 2 + kk) * 512 + lrO + gsw8];
#define LD_B(nq)                                                               \
    _Pragma("unroll") for (int nf = 0; nf < 2; ++nf)                           \
    _Pragma("unroll") for (int kk = 0; kk < 2; ++kk)                           \
        bf[nf][kk] = *(const short8*)&LDS[curS + 16384 +                       \
            ((wn * 4 + (nq) * 2 + nf) * 2 + kk) * 512 + lrO + gsw8];
#define QMM(mq, nq)                                                            \
    _Pragma("unroll") for (int kk = 0; kk < 2; ++kk)                           \
    _Pragma("unroll") for (int mf = 0; mf < 4; ++mf)                           \
    _Pragma("unroll") for (int nf = 0; nf < 2; ++nf)                           \
        acc[(mq) * 4 + mf][(nq) * 2 + nf] =                                    \
            __builtin_amdgcn_mfma_f32_16x16x32_bf16(af[mf][kk], bf[nf][kk],    \
                acc[(mq) * 4 + mf][(nq) * 2 + nf], 0, 0, 0);

    f32x4 acc[8][4] = {};
    short8 af[4][2], bf[2][2];
    // prologue: tile0 all 4 groups (8 loads), tile1 {A-g0, B-nq1, A-g1}
    // (6 loads; B-nq0(1) is staged at P1(0)). vmcnt(6) = tile0 landed.
    STG(ABASE(0), 0, stA0);
    STG(BBASE(0), 16384, stB_P1);
    STG(BBASE(0), 16384, stB_P3);
    STG(ABASE(0), 0, stA1);
    STG(ABASE(1), 32768, stA0);
    STG(BBASE(1), 49152, stB_P3);
    STG(ABASE(1), 32768, stA1);
    asm volatile("s_waitcnt vmcnt(6)" ::: "memory");   // tile0 complete
#pragma unroll 2
    for (int t = 0; t < NT; ++t) {
        const int curS = (t & 1) * 32768;
        const int nxtS = curS ^ 32768;
        // ---- P1: Q(0,0) ----
        __builtin_amdgcn_s_barrier();
        LD_A(0); LD_B(0);
        __builtin_amdgcn_s_setprio(1); QMM(0, 0); __builtin_amdgcn_s_setprio(0);
        if (t + 1 < NT) STG(BBASE(t + 1), nxtS + 16384, stB_P1);
        // ---- P2: Q(0,1) ----
        __builtin_amdgcn_s_barrier();
        LD_B(1);
        __builtin_amdgcn_s_setprio(1); QMM(0, 1); __builtin_amdgcn_s_setprio(0);
        if (t + 2 < NT) STG(ABASE(t + 2), curS, stA0);
        // ---- P3: Q(1,1) ----
        __builtin_amdgcn_s_barrier();
        LD_A(1);
        __builtin_amdgcn_s_setprio(1); QMM(1, 1); __builtin_amdgcn_s_setprio(0);
        if (t + 2 < NT) STG(BBASE(t + 2), curS + 16384, stB_P3);
        // ---- P4: Q(1,0) ----
        __builtin_amdgcn_s_barrier();
        LD_B(0);
        __builtin_amdgcn_s_setprio(1); QMM(1, 0); __builtin_amdgcn_s_setprio(0);
        if (t + 2 < NT) STG(ABASE(t + 2), curS, stA1);
        // fence: tile t+1 fully landed; tile t+2's groups stay in flight
        if (t < NT - 2) {
            asm volatile("s_waitcnt vmcnt(6)" ::: "memory");
        } else {
            asm volatile("s_waitcnt vmcnt(0)" ::: "memory");
        }
    }
    // epilogue: C/D layout col=lane&15, row=(lane>>4)*4+j (HW-verified)
#pragma unroll
    for (int mf = 0; mf < 8; ++mf) {
        const int grow = m0 + wm * 128 + mf * 16 + (lane >> 4) * 4;
#pragma unroll
        for (int nf = 0; nf < 4; ++nf) {
            const int gcol = n0 + wn * 64 + nf * 16 + lr;
            unsigned short* Cp = C + (size_t)grow * H_DIM + gcol;
#pragma unroll
            for (int j = 0; j < 4; ++j) Cp[(size_t)j * H_DIM] = f2bf(acc[mf][nf][j]);
        }
    }
#undef STG
#undef ABASE
#undef BBASE
#undef LD_A
#undef LD_B
#undef QMM
}

// ---------- rmsnorm + exact gelu, one wave per 1024-wide row ----------
__global__ __launch_bounds__(256)
void norm_gelu(const unsigned short* __restrict__ Hp, const float* __restrict__ g,
               unsigned short* __restrict__ U) {
    const int row = blockIdx.x * 4 + (threadIdx.x >> 6);
    const int lane = threadIdx.x & 63;
    const unsigned short* rp = Hp + (size_t)row * H_DIM;
    short8 v0 = *(const short8*)(rp + lane * 8);
    short8 v1 = *(const short8*)(rp + 512 + lane * 8);
    float f[16];
#pragma unroll
    for (int j = 0; j < 8; ++j) {
        f[j] = bf2f((unsigned short)v0[j]);
        f[8 + j] = bf2f((unsigned short)v1[j]);
    }
    float s = 0.f;
#pragma unroll
    for (int j = 0; j < 16; ++j) s += f[j] * f[j];
#pragma unroll
    for (int o = 32; o > 0; o >>= 1) s += __shfl_xor(s, o);
    const float rinv = 1.f / sqrtf(s * (1.f / 1024.f) + 1e-6f);
    short8 o0, o1;
#pragma unroll
    for (int j = 0; j < 8; ++j) {
        const int c0 = lane * 8 + j, c1 = 512 + lane * 8 + j;
        float t0 = f[j] * rinv * g[c0];
        float t1 = f[8 + j] * rinv * g[c1];
        float u0 = 0.5f * t0 * (1.f + erff(t0 * 0.70710678118f));
        float u1 = 0.5f * t1 * (1.f + erff(t1 * 0.70710678118f));
        o0[j] = (short)f2bf(u0);
        o1[j] = (short)f2bf(u1);
    }
    unsigned short* up = U + (size_t)row * H_DIM;
    *(short8*)(up + lane * 8) = o0;
    *(short8*)(up + 512 + lane * 8) = o1;
}

// ---------- final layer: out[M x 10] = A[M x 1024] * w3q[16 x 1024]^T ----------
__global__ __launch_bounds__(256)
void gemm3_kernel(const unsigned short* __restrict__ A, const unsigned short* __restrict__ Bq,
                  float* __restrict__ out) {
    __shared__ unsigned short As[128][40];
    __shared__ unsigned short Bs[16][40];
    const int tid = threadIdx.x;
    const int lane = tid & 63;
    const int wid = tid >> 6;
    const int m0 = blockIdx.x * 128;
    const int lr = lane & 15;
    const int lk = (lane >> 4) * 8;
    const int sr = tid >> 2;
    const int sc = (tid & 3) * 8;
    f32x4 acc[2] = {};
    for (int kt = 0; kt < 32; ++kt) {
        const int kb = kt * 32;
        __syncthreads();
#pragma unroll
        for (int p = 0; p < 2; ++p) {
            const int r = p * 64 + sr;
            *(short8*)&As[r][sc] = *(const short8*)(A + (size_t)(m0 + r) * H_DIM + kb + sc);
        }
        if (tid < 64) {
            const int r = tid >> 2;
            const int c = (tid & 3) * 8;
            *(short8*)&Bs[r][c] = *(const short8*)(Bq + (size_t)r * H_DIM + kb + c);
        }
        __syncthreads();
        short8 bv = *(const short8*)&Bs[lr][lk];
#pragma unroll
        for (int m = 0; m < 2; ++m) {
            short8 a = *(const short8*)&As[wid * 32 + m * 16 + lr][lk];
            acc[m] = __builtin_amdgcn_mfma_f32_16x16x32_bf16(a, bv, acc[m], 0, 0, 0);
        }
    }
    if (lr < OUT_DIM) {
#pragma unroll
        for (int m = 0; m < 2; ++m)
#pragma unroll
            for (int j = 0; j < 4; ++j) {
                const int grow = m0 + wid * 32 + m * 16 + (lane >> 4) * 4 + j;
                out[(size_t)grow * OUT_DIM + lr] = acc[m][j];
            }
    }
}

extern "C" void kernel_launch(void* const* d_in, const int* in_sizes, int n_in,
                              void* d_out, int out_size, void* d_ws, size_t ws_size,
                              hipStream_t stream) {
    (void)in_sizes; (void)n_in; (void)out_size;
    const float* x  = (const float*)d_in[0];
    const float* w1 = (const float*)d_in[1];
    const float* g1 = (const float*)d_in[2];
    const float* w2 = (const float*)d_in[3];
    const float* g2 = (const float*)d_in[4];
    const float* w3 = (const float*)d_in[5];
    float* out = (float*)d_out;

    uint8_t* ws = (uint8_t*)d_ws;
    double* sums = (double*)ws;
    size_t off = 256;
    unsigned short* w1q = (unsigned short*)(ws + off); off += (size_t)H_DIM * IN_PAD * 2;
    unsigned short* w2q = (unsigned short*)(ws + off); off += (size_t)H_DIM * H_DIM * 2;
    unsigned short* w3q = (unsigned short*)(ws + off); off += (size_t)OUT_PAD * H_DIM * 2;

    // largest pow2 chunk R (multiple of 2048 for the 256-tile XCD swizzle) whose
    // two bf16 [R x 1024] buffers fit; bufB doubles as the bf16 x-chunk [R x 896]
    size_t rem = (ws_size > off) ? ws_size - off : 0;
    int R = B_TOTAL;
    while (R > 2048 && (size_t)2 * R * H_DIM * 2 > rem) R >>= 1;
    unsigned short* bufA = (unsigned short*)(ws + off);
    unsigned short* bufB = bufA + (size_t)R * H_DIM;

    hipMemsetAsync(sums, 0, 3 * sizeof(double), stream);
    absum_kernel<<<128, 256, 0, stream>>>(w1, H_DIM * IN_DIM, sums + 0);
    absum_kernel<<<128, 256, 0, stream>>>(w2, H_DIM * H_DIM, sums + 1);
    absum_kernel<<<128, 256, 0, stream>>>(w3, OUT_DIM * H_DIM, sums + 2);
    quant_kernel<<<dim3((IN_PAD + 255) / 256, H_DIM), 256, 0, stream>>>(
        w1, w1q, H_DIM, IN_DIM, IN_PAD, sums + 0, H_DIM * IN_DIM);
    quant_kernel<<<dim3((H_DIM + 255) / 256, H_DIM), 256, 0, stream>>>(
        w2, w2q, H_DIM, H_DIM, H_DIM, sums + 1, H_DIM * H_DIM);
    quant_kernel<<<dim3((H_DIM + 255) / 256, OUT_PAD), 256, 0, stream>>>(
        w3, w3q, OUT_DIM, H_DIM, H_DIM, sums + 2, OUT_DIM * H_DIM);

    const int nchunk = B_TOTAL / R;
    for (int c = 0; c < nchunk; ++c) {
        const float* xc = x + (size_t)c * R * IN_DIM;
        convert_pad<<<R * 112 / 256, 256, 0, stream>>>(xc, bufB);
        gemm_bt<IN_PAD><<<(R / 256) * 4, 512, 0, stream>>>(bufB, w1q, bufA);
        norm_gelu<<<R / 4, 256, 0, stream>>>(bufA, g1, bufB);
        gemm_bt<H_DIM><<<(R / 256) * 4, 512, 0, stream>>>(bufB, w2q, bufA);
        norm_gelu<<<R / 4, 256, 0, stream>>>(bufA, g2, bufB);
        gemm3_kernel<<<R / 128, 256, 0, stream>>>(bufB, w3q, out + (size_t)c * R * OUT_DIM);
    }
}

// Round 8
// 490.863 us; speedup vs baseline: 1.7771x; 1.2770x over previous
//
#include <hip/hip_runtime.h>
#include <hip/hip_bf16.h>
#include <stdint.h>

// BitNet MNIST MLP, Round 7: r6 GEMM structure kept verbatim (149us/gemm plateau);
// this round attacks the 348us of non-GEMM time:
//  - norm_gelu: A&S 7.1.26 rational erf (|eps|<=1.5e-7) replaces libm erff
//    (was ~30+ VALU instrs x 67M calls = VALU-bound ~100us/launch).
//  - gemm3: w3q staged to LDS once (padded, <=2-way conflicts), A direct
//    global->reg (16 rows x 64B coalesced), no barriers in K-loop.

typedef __attribute__((ext_vector_type(8))) short short8;
typedef __attribute__((ext_vector_type(4))) float f32x4;

#define B_TOTAL 65536
#define IN_DIM 784
#define IN_PAD 896
#define H_DIM 1024
#define OUT_DIM 10
#define OUT_PAD 16

__device__ __forceinline__ unsigned short f2bf(float f) {
    union { float f; unsigned u; } c; c.f = f;
    unsigned r = c.u + 0x7FFFu + ((c.u >> 16) & 1u);
    return (unsigned short)(r >> 16);
}
__device__ __forceinline__ float bf2f(unsigned short h) {
    union { unsigned u; float f; } c; c.u = ((unsigned)h) << 16;
    return c.f;
}

// exact-gelu via A&S 7.1.26 erf approximation, |eps| <= 1.5e-7 (far below
// bf16 output resolution -> numerically identical to erff at bf16).
__device__ __forceinline__ float gelu_fast(float t) {
    const float z = t * 0.70710678118f;
    const float s = fabsf(z);
    const float tt = 1.0f / (1.0f + 0.3275911f * s);
    const float e = __expf(-s * s);
    float p = fmaf(tt, 1.061405429f, -1.453152027f);
    p = fmaf(tt, p, 1.421413741f);
    p = fmaf(tt, p, -0.284496736f);
    p = fmaf(tt, p, 0.254829592f);
    float erfa = fmaf(-p * tt, e, 1.0f);          // erf(|z|)
    erfa = copysignf(erfa, z);
    return 0.5f * t * (1.0f + erfa);
}

#define GLOAD16(gp, lp)                                                        \
    __builtin_amdgcn_global_load_lds(                                          \
        (const __attribute__((address_space(1))) void*)(gp),                   \
        (__attribute__((address_space(3))) void*)(lp), 16, 0, 0)

// ---------- weight |w| sum (double atomic: deterministic) ----------
__global__ void absum_kernel(const float* __restrict__ w, int n, double* acc) {
    __shared__ float red[4];
    float s = 0.f;
    for (int i = blockIdx.x * blockDim.x + threadIdx.x; i < n; i += gridDim.x * blockDim.x)
        s += fabsf(w[i]);
#pragma unroll
    for (int o = 32; o > 0; o >>= 1) s += __shfl_xor(s, o);
    if ((threadIdx.x & 63) == 0) red[threadIdx.x >> 6] = s;
    __syncthreads();
    if (threadIdx.x == 0) {
        float t = red[0] + red[1] + red[2] + red[3];
        atomicAdd(acc, (double)t);
    }
}

// ---------- ternary quantize -> bf16, pad K to Kp and O rows up ----------
__global__ void quant_kernel(const float* __restrict__ w, unsigned short* __restrict__ wq,
                             int O, int K, int Kp, const double* sum, int n) {
    int k = blockIdx.x * blockDim.x + threadIdx.x;
    int o = blockIdx.y;
    if (k >= Kp) return;
    float scale = fmaxf((float)(*sum / (double)n), 1e-5f);
    float q = 0.f;
    if (o < O && k < K) {
        float r = rintf(w[(size_t)o * K + k] / scale);  // round-half-even == jnp.round
        q = fminf(1.f, fmaxf(-1.f, r));
    }
    wq[(size_t)o * Kp + k] = f2bf(q);
}

// ---------- x fp32 [R x 784] -> bf16 [R x 896] (zero-padded) ----------
__global__ __launch_bounds__(256)
void convert_pad(const float* __restrict__ x, unsigned short* __restrict__ xb) {
    const int g = blockIdx.x * 256 + threadIdx.x;   // one 8-col group per thread
    const int row = g / 112;
    const int c = (g % 112) * 8;
    short8 v = 0;
    if (c < IN_DIM) {
        const float* p = x + (size_t)row * IN_DIM + c;
        float4 f0 = *(const float4*)p;
        float4 f1 = *(const float4*)(p + 4);
        v[0] = (short)f2bf(f0.x); v[1] = (short)f2bf(f0.y);
        v[2] = (short)f2bf(f0.z); v[3] = (short)f2bf(f0.w);
        v[4] = (short)f2bf(f1.x); v[5] = (short)f2bf(f1.y);
        v[6] = (short)f2bf(f1.z); v[7] = (short)f2bf(f1.w);
    }
    *(short8*)(xb + (size_t)row * IN_PAD + c) = v;
}

// ---------- GEMM: C[M x 1024] = A[M x KP] * Bq[1024 x KP]^T ----------
// (unchanged from round 6 -- verified passing)
template<int KP>
__global__ __launch_bounds__(512, 2)
void gemm_bt(const unsigned short* __restrict__ A, const unsigned short* __restrict__ Bq,
             unsigned short* __restrict__ C) {
    constexpr int NT = KP / 64;
    __shared__ __attribute__((aligned(16))) unsigned short LDS[65536];  // 128 KB
    const int tid = threadIdx.x;
    const int lane = tid & 63;
    const int w = tid >> 6;
    const int wm = w >> 2, wn = w & 3;
    const int lr = lane & 15, gq = lane >> 4;
    const int gsw8 = (gq ^ ((lr >> 3) << 1)) * 8;   // swizzled granule offset (shorts)
    const int lrO = lr * 32;
    const int bid = blockIdx.x;
    const int xcd = bid & 7, slot = bid >> 3;
    const int nblk = slot & 3;
    const int mblk = xcd * (gridDim.x >> 5) + (slot >> 2);
    const int m0 = mblk * 256, n0 = nblk * 256;
    const int rS = lane >> 2;                              // row within 16-row subtile
    const int cS = ((lane & 3) ^ ((lane >> 5) << 1)) * 8;  // swizzled col granule
    const int stA0 = w;                          // A-g0: read @P1 (LD_A(0))
    const int stA1 = 8 + w;                      // A-g1: read @P3 (LD_A(1))
    const int stB_P1 = (w >> 2) * 8 + (w & 3);   // B-nq0: read @P1,P4 (LD_B(0))
    const int stB_P3 = stB_P1 + 4;               // B-nq1: read @P2 (LD_B(1))

#define STG(gbase, areaS, st)                                                  \
    {   const unsigned short* _g = (gbase) +                                   \
            (size_t)(((st) >> 1) * 16 + rS) * KP + ((st) & 1) * 32 + cS;       \
        GLOAD16(_g, &LDS[(areaS) + (st) * 512]);                               \
        GLOAD16(_g + (size_t)128 * KP, &LDS[(areaS) + (st) * 512 + 8192]); }
#define ABASE(t) (A + (size_t)m0 * KP + (t) * 64)
#define BBASE(t) (Bq + (size_t)n0 * KP + (t) * 64)
#define LD_A(mq)                                                               \
    _Pragma("unroll") for (int mf = 0; mf < 4; ++mf)                           \
    _Pragma("unroll") for (int kk = 0; kk < 2; ++kk)                           \
        af[mf][kk] = *(const short8*)&LDS[curS +                               \
            ((wm * 8 + (mq) * 4 + mf) * 2 + kk) * 512 + lrO + gsw8];
#define LD_B(nq)                                                               \
    _Pragma("unroll") for (int nf = 0; nf < 2; ++nf)                           \
    _Pragma("unroll") for (int kk = 0; kk < 2; ++kk)                           \
        bf[nf][kk] = *(const short8*)&LDS[curS + 16384 +                       \
            ((wn * 4 + (nq) * 2 + nf) * 2 + kk) * 512 + lrO + gsw8];
#define QMM(mq, nq)                                                            \
    _Pragma("unroll") for (int kk = 0; kk < 2; ++kk)                           \
    _Pragma("unroll") for (int mf = 0; mf < 4; ++mf)                           \
    _Pragma("unroll") for (int nf = 0; nf < 2; ++nf)                           \
        acc[(mq) * 4 + mf][(nq) * 2 + nf] =                                    \
            __builtin_amdgcn_mfma_f32_16x16x32_bf16(af[mf][kk], bf[nf][kk],    \
                acc[(mq) * 4 + mf][(nq) * 2 + nf], 0, 0, 0);

    f32x4 acc[8][4] = {};
    short8 af[4][2], bf[2][2];
    STG(ABASE(0), 0, stA0);
    STG(BBASE(0), 16384, stB_P1);
    STG(BBASE(0), 16384, stB_P3);
    STG(ABASE(0), 0, stA1);
    STG(ABASE(1), 32768, stA0);
    STG(BBASE(1), 49152, stB_P3);
    STG(ABASE(1), 32768, stA1);
    asm volatile("s_waitcnt vmcnt(6)" ::: "memory");   // tile0 complete
#pragma unroll 2
    for (int t = 0; t < NT; ++t) {
        const int curS = (t & 1) * 32768;
        const int nxtS = curS ^ 32768;
        // ---- P1: Q(0,0) ----
        __builtin_amdgcn_s_barrier();
        LD_A(0); LD_B(0);
        __builtin_amdgcn_s_setprio(1); QMM(0, 0); __builtin_amdgcn_s_setprio(0);
        if (t + 1 < NT) STG(BBASE(t + 1), nxtS + 16384, stB_P1);
        // ---- P2: Q(0,1) ----
        __builtin_amdgcn_s_barrier();
        LD_B(1);
        __builtin_amdgcn_s_setprio(1); QMM(0, 1); __builtin_amdgcn_s_setprio(0);
        if (t + 2 < NT) STG(ABASE(t + 2), curS, stA0);
        // ---- P3: Q(1,1) ----
        __builtin_amdgcn_s_barrier();
        LD_A(1);
        __builtin_amdgcn_s_setprio(1); QMM(1, 1); __builtin_amdgcn_s_setprio(0);
        if (t + 2 < NT) STG(BBASE(t + 2), curS + 16384, stB_P3);
        // ---- P4: Q(1,0) ----
        __builtin_amdgcn_s_barrier();
        LD_B(0);
        __builtin_amdgcn_s_setprio(1); QMM(1, 0); __builtin_amdgcn_s_setprio(0);
        if (t + 2 < NT) STG(ABASE(t + 2), curS, stA1);
        if (t < NT - 2) {
            asm volatile("s_waitcnt vmcnt(6)" ::: "memory");
        } else {
            asm volatile("s_waitcnt vmcnt(0)" ::: "memory");
        }
    }
#pragma unroll
    for (int mf = 0; mf < 8; ++mf) {
        const int grow = m0 + wm * 128 + mf * 16 + (lane >> 4) * 4;
#pragma unroll
        for (int nf = 0; nf < 4; ++nf) {
            const int gcol = n0 + wn * 64 + nf * 16 + lr;
            unsigned short* Cp = C + (size_t)grow * H_DIM + gcol;
#pragma unroll
            for (int j = 0; j < 4; ++j) Cp[(size_t)j * H_DIM] = f2bf(acc[mf][nf][j]);
        }
    }
#undef STG
#undef ABASE
#undef BBASE
#undef LD_A
#undef LD_B
#undef QMM
}

// ---------- rmsnorm + exact gelu (fast erf), one wave per 1024-wide row ----------
__global__ __launch_bounds__(256)
void norm_gelu(const unsigned short* __restrict__ Hp, const float* __restrict__ g,
               unsigned short* __restrict__ U) {
    const int row = blockIdx.x * 4 + (threadIdx.x >> 6);
    const int lane = threadIdx.x & 63;
    const unsigned short* rp = Hp + (size_t)row * H_DIM;
    short8 v0 = *(const short8*)(rp + lane * 8);
    short8 v1 = *(const short8*)(rp + 512 + lane * 8);
    float f[16];
#pragma unroll
    for (int j = 0; j < 8; ++j) {
        f[j] = bf2f((unsigned short)v0[j]);
        f[8 + j] = bf2f((unsigned short)v1[j]);
    }
    float s = 0.f;
#pragma unroll
    for (int j = 0; j < 16; ++j) s += f[j] * f[j];
#pragma unroll
    for (int o = 32; o > 0; o >>= 1) s += __shfl_xor(s, o);
    const float rinv = 1.f / sqrtf(s * (1.f / 1024.f) + 1e-6f);
    float4 ga0 = *(const float4*)(g + lane * 8);
    float4 ga1 = *(const float4*)(g + lane * 8 + 4);
    float4 gb0 = *(const float4*)(g + 512 + lane * 8);
    float4 gb1 = *(const float4*)(g + 512 + lane * 8 + 4);
    float gv[16] = {ga0.x, ga0.y, ga0.z, ga0.w, ga1.x, ga1.y, ga1.z, ga1.w,
                    gb0.x, gb0.y, gb0.z, gb0.w, gb1.x, gb1.y, gb1.z, gb1.w};
    short8 o0, o1;
#pragma unroll
    for (int j = 0; j < 8; ++j) {
        o0[j] = (short)f2bf(gelu_fast(f[j] * rinv * gv[j]));
        o1[j] = (short)f2bf(gelu_fast(f[8 + j] * rinv * gv[8 + j]));
    }
    unsigned short* up = U + (size_t)row * H_DIM;
    *(short8*)(up + lane * 8) = o0;
    *(short8*)(up + 512 + lane * 8) = o1;
}

// ---------- final layer: out[M x 10] = A[M x 1024] * w3q[16 x 1024]^T ----------
// w3q staged to LDS once (padded row stride 1032 -> <=2-way conflicts);
// A fragments loaded global->reg directly (16 rows x 64B coalesced);
// no barriers in the K-loop -> compiler software-pipelines.
__global__ __launch_bounds__(256)
void gemm3_kernel(const unsigned short* __restrict__ A, const unsigned short* __restrict__ Bq,
                  float* __restrict__ out) {
    __shared__ unsigned short Bs[16][1032];
    const int tid = threadIdx.x;
    const int lane = tid & 63;
    const int wid = tid >> 6;
    for (int i = tid; i < 2048; i += 256) {           // 16 rows x 128 short8-groups
        const int r = i >> 7, cg = i & 127;
        *(short8*)&Bs[r][cg * 8] = *(const short8*)(Bq + (size_t)r * H_DIM + cg * 8);
    }
    __syncthreads();
    const int m0 = blockIdx.x * 128 + wid * 32;
    const int lr = lane & 15;
    const int lk = (lane >> 4) * 8;
    f32x4 acc[2] = {};
#pragma unroll 4
    for (int ks = 0; ks < 32; ++ks) {
        short8 bv = *(const short8*)&Bs[lr][ks * 32 + lk];
#pragma unroll
        for (int m = 0; m < 2; ++m) {
            short8 a = *(const short8*)(A + (size_t)(m0 + m * 16 + lr) * H_DIM + ks * 32 + lk);
            acc[m] = __builtin_amdgcn_mfma_f32_16x16x32_bf16(a, bv, acc[m], 0, 0, 0);
        }
    }
    if (lr < OUT_DIM) {
#pragma unroll
        for (int m = 0; m < 2; ++m)
#pragma unroll
            for (int j = 0; j < 4; ++j) {
                const int grow = m0 + m * 16 + (lane >> 4) * 4 + j;
                out[(size_t)grow * OUT_DIM + lr] = acc[m][j];
            }
    }
}

extern "C" void kernel_launch(void* const* d_in, const int* in_sizes, int n_in,
                              void* d_out, int out_size, void* d_ws, size_t ws_size,
                              hipStream_t stream) {
    (void)in_sizes; (void)n_in; (void)out_size;
    const float* x  = (const float*)d_in[0];
    const float* w1 = (const float*)d_in[1];
    const float* g1 = (const float*)d_in[2];
    const float* w2 = (const float*)d_in[3];
    const float* g2 = (const float*)d_in[4];
    const float* w3 = (const float*)d_in[5];
    float* out = (float*)d_out;

    uint8_t* ws = (uint8_t*)d_ws;
    double* sums = (double*)ws;
    size_t off = 256;
    unsigned short* w1q = (unsigned short*)(ws + off); off += (size_t)H_DIM * IN_PAD * 2;
    unsigned short* w2q = (unsigned short*)(ws + off); off += (size_t)H_DIM * H_DIM * 2;
    unsigned short* w3q = (unsigned short*)(ws + off); off += (size_t)OUT_PAD * H_DIM * 2;

    size_t rem = (ws_size > off) ? ws_size - off : 0;
    int R = B_TOTAL;
    while (R > 2048 && (size_t)2 * R * H_DIM * 2 > rem) R >>= 1;
    unsigned short* bufA = (unsigned short*)(ws + off);
    unsigned short* bufB = bufA + (size_t)R * H_DIM;

    hipMemsetAsync(sums, 0, 3 * sizeof(double), stream);
    absum_kernel<<<128, 256, 0, stream>>>(w1, H_DIM * IN_DIM, sums + 0);
    absum_kernel<<<128, 256, 0, stream>>>(w2, H_DIM * H_DIM, sums + 1);
    absum_kernel<<<128, 256, 0, stream>>>(w3, OUT_DIM * H_DIM, sums + 2);
    quant_kernel<<<dim3((IN_PAD + 255) / 256, H_DIM), 256, 0, stream>>>(
        w1, w1q, H_DIM, IN_DIM, IN_PAD, sums + 0, H_DIM * IN_DIM);
    quant_kernel<<<dim3((H_DIM + 255) / 256, H_DIM), 256, 0, stream>>>(
        w2, w2q, H_DIM, H_DIM, H_DIM, sums + 1, H_DIM * H_DIM);
    quant_kernel<<<dim3((H_DIM + 255) / 256, OUT_PAD), 256, 0, stream>>>(
        w3, w3q, OUT_DIM, H_DIM, H_DIM, sums + 2, OUT_DIM * H_DIM);

    const int nchunk = B_TOTAL / R;
    for (int c = 0; c < nchunk; ++c) {
        const float* xc = x + (size_t)c * R * IN_DIM;
        convert_pad<<<R * 112 / 256, 256, 0, stream>>>(xc, bufB);
        gemm_bt<IN_PAD><<<(R / 256) * 4, 512, 0, stream>>>(bufB, w1q, bufA);
        norm_gelu<<<R / 4, 256, 0, stream>>>(bufA, g1, bufB);
        gemm_bt<H_DIM><<<(R / 256) * 4, 512, 0, stream>>>(bufB, w2q, bufA);
        norm_gelu<<<R / 4, 256, 0, stream>>>(bufA, g2, bufB);
        gemm3_kernel<<<R / 128, 256, 0, stream>>>(bufB, w3q, out + (size_t)c * R * OUT_DIM);
    }
}

// Round 9
// 463.082 us; speedup vs baseline: 1.8837x; 1.0600x over previous
//
#include <hip/hip_runtime.h>
#include <hip/hip_bf16.h>
#include <stdint.h>

// BitNet MNIST MLP, Round 8: r7 GEMM/convert/norm1 kept verbatim. Fusions:
//  - norm_gelu_out: rmsnorm+gelu+final-GEMM fused (u2 never hits global;
//    per-16-row block: 4 waves norm->LDS, wave0 does 32 MFMAs for the 10 outs).
//  - absum x3 -> 1 kernel (grid.y), quant x3 -> 1 kernel (grid.y row ranges).

typedef __attribute__((ext_vector_type(8))) short short8;
typedef __attribute__((ext_vector_type(4))) float f32x4;

#define B_TOTAL 65536
#define IN_DIM 784
#define IN_PAD 896
#define H_DIM 1024
#define OUT_DIM 10
#define OUT_PAD 16

__device__ __forceinline__ unsigned short f2bf(float f) {
    union { float f; unsigned u; } c; c.f = f;
    unsigned r = c.u + 0x7FFFu + ((c.u >> 16) & 1u);
    return (unsigned short)(r >> 16);
}
__device__ __forceinline__ float bf2f(unsigned short h) {
    union { unsigned u; float f; } c; c.u = ((unsigned)h) << 16;
    return c.f;
}

// exact-gelu via A&S 7.1.26 erf approximation, |eps| <= 1.5e-7.
__device__ __forceinline__ float gelu_fast(float t) {
    const float z = t * 0.70710678118f;
    const float s = fabsf(z);
    const float tt = 1.0f / (1.0f + 0.3275911f * s);
    const float e = __expf(-s * s);
    float p = fmaf(tt, 1.061405429f, -1.453152027f);
    p = fmaf(tt, p, 1.421413741f);
    p = fmaf(tt, p, -0.284496736f);
    p = fmaf(tt, p, 0.254829592f);
    float erfa = fmaf(-p * tt, e, 1.0f);          // erf(|z|)
    erfa = copysignf(erfa, z);
    return 0.5f * t * (1.0f + erfa);
}

#define GLOAD16(gp, lp)                                                        \
    __builtin_amdgcn_global_load_lds(                                          \
        (const __attribute__((address_space(1))) void*)(gp),                   \
        (__attribute__((address_space(3))) void*)(lp), 16, 0, 0)

// ---------- |w| sums for all 3 weights (grid.y selects; double atomics) ----------
__global__ void absum3_kernel(const float* __restrict__ w1, const float* __restrict__ w2,
                              const float* __restrict__ w3, double* acc) {
    __shared__ float red[4];
    const int which = blockIdx.y;
    const float* w = (which == 0) ? w1 : (which == 1) ? w2 : w3;
    const int n = (which == 0) ? H_DIM * IN_DIM : (which == 1) ? H_DIM * H_DIM : OUT_DIM * H_DIM;
    float s = 0.f;
    for (int i = blockIdx.x * blockDim.x + threadIdx.x; i < n; i += gridDim.x * blockDim.x)
        s += fabsf(w[i]);
#pragma unroll
    for (int o = 32; o > 0; o >>= 1) s += __shfl_xor(s, o);
    if ((threadIdx.x & 63) == 0) red[threadIdx.x >> 6] = s;
    __syncthreads();
    if (threadIdx.x == 0) {
        float t = red[0] + red[1] + red[2] + red[3];
        atomicAdd(acc + which, (double)t);
    }
}

// ---------- ternary quantize all 3 weights -> bf16 (grid.y = flat row) ----------
__global__ void quant_all(const float* __restrict__ w1, const float* __restrict__ w2,
                          const float* __restrict__ w3,
                          unsigned short* __restrict__ w1q, unsigned short* __restrict__ w2q,
                          unsigned short* __restrict__ w3q, const double* sums) {
    const int k = blockIdx.x * blockDim.x + threadIdx.x;
    const int y = blockIdx.y;
    const float* w; unsigned short* wq; int o, O, K, Kp, n; const double* sum;
    if (y < 1024)      { w = w1; wq = w1q; o = y;        O = H_DIM;  K = IN_DIM; Kp = IN_PAD; n = H_DIM * IN_DIM;  sum = sums + 0; }
    else if (y < 2048) { w = w2; wq = w2q; o = y - 1024; O = H_DIM;  K = H_DIM;  Kp = H_DIM;  n = H_DIM * H_DIM;  sum = sums + 1; }
    else               { w = w3; wq = w3q; o = y - 2048; O = OUT_DIM; K = H_DIM; Kp = H_DIM;  n = OUT_DIM * H_DIM; sum = sums + 2; }
    if (k >= Kp) return;
    float scale = fmaxf((float)(*sum / (double)n), 1e-5f);
    float q = 0.f;
    if (o < O && k < K) {
        float r = rintf(w[(size_t)o * K + k] / scale);  // round-half-even == jnp.round
        q = fminf(1.f, fmaxf(-1.f, r));
    }
    wq[(size_t)o * Kp + k] = f2bf(q);
}

// ---------- x fp32 [R x 784] -> bf16 [R x 896] (zero-padded) ----------
__global__ __launch_bounds__(256)
void convert_pad(const float* __restrict__ x, unsigned short* __restrict__ xb) {
    const int g = blockIdx.x * 256 + threadIdx.x;   // one 8-col group per thread
    const int row = g / 112;
    const int c = (g % 112) * 8;
    short8 v = 0;
    if (c < IN_DIM) {
        const float* p = x + (size_t)row * IN_DIM + c;
        float4 f0 = *(const float4*)p;
        float4 f1 = *(const float4*)(p + 4);
        v[0] = (short)f2bf(f0.x); v[1] = (short)f2bf(f0.y);
        v[2] = (short)f2bf(f0.z); v[3] = (short)f2bf(f0.w);
        v[4] = (short)f2bf(f1.x); v[5] = (short)f2bf(f1.y);
        v[6] = (short)f2bf(f1.z); v[7] = (short)f2bf(f1.w);
    }
    *(short8*)(xb + (size_t)row * IN_PAD + c) = v;
}

// ---------- GEMM: C[M x 1024] = A[M x KP] * Bq[1024 x KP]^T ----------
// (unchanged from round 6/7 -- verified passing)
template<int KP>
__global__ __launch_bounds__(512, 2)
void gemm_bt(const unsigned short* __restrict__ A, const unsigned short* __restrict__ Bq,
             unsigned short* __restrict__ C) {
    constexpr int NT = KP / 64;
    __shared__ __attribute__((aligned(16))) unsigned short LDS[65536];  // 128 KB
    const int tid = threadIdx.x;
    const int lane = tid & 63;
    const int w = tid >> 6;
    const int wm = w >> 2, wn = w & 3;
    const int lr = lane & 15, gq = lane >> 4;
    const int gsw8 = (gq ^ ((lr >> 3) << 1)) * 8;   // swizzled granule offset (shorts)
    const int lrO = lr * 32;
    const int bid = blockIdx.x;
    const int xcd = bid & 7, slot = bid >> 3;
    const int nblk = slot & 3;
    const int mblk = xcd * (gridDim.x >> 5) + (slot >> 2);
    const int m0 = mblk * 256, n0 = nblk * 256;
    const int rS = lane >> 2;                              // row within 16-row subtile
    const int cS = ((lane & 3) ^ ((lane >> 5) << 1)) * 8;  // swizzled col granule
    const int stA0 = w;                          // A-g0: read @P1 (LD_A(0))
    const int stA1 = 8 + w;                      // A-g1: read @P3 (LD_A(1))
    const int stB_P1 = (w >> 2) * 8 + (w & 3);   // B-nq0: read @P1,P4 (LD_B(0))
    const int stB_P3 = stB_P1 + 4;               // B-nq1: read @P2 (LD_B(1))

#define STG(gbase, areaS, st)                                                  \
    {   const unsigned short* _g = (gbase) +                                   \
            (size_t)(((st) >> 1) * 16 + rS) * KP + ((st) & 1) * 32 + cS;       \
        GLOAD16(_g, &LDS[(areaS) + (st) * 512]);                               \
        GLOAD16(_g + (size_t)128 * KP, &LDS[(areaS) + (st) * 512 + 8192]); }
#define ABASE(t) (A + (size_t)m0 * KP + (t) * 64)
#define BBASE(t) (Bq + (size_t)n0 * KP + (t) * 64)
#define LD_A(mq)                                                               \
    _Pragma("unroll") for (int mf = 0; mf < 4; ++mf)                           \
    _Pragma("unroll") for (int kk = 0; kk < 2; ++kk)                           \
        af[mf][kk] = *(const short8*)&LDS[curS +                               \
            ((wm * 8 + (mq) * 4 + mf) * 2 + kk) * 512 + lrO + gsw8];
#define LD_B(nq)                                                               \
    _Pragma("unroll") for (int nf = 0; nf < 2; ++nf)                           \
    _Pragma("unroll") for (int kk = 0; kk < 2; ++kk)                           \
        bf[nf][kk] = *(const short8*)&LDS[curS + 16384 +                       \
            ((wn * 4 + (nq) * 2 + nf) * 2 + kk) * 512 + lrO + gsw8];
#define QMM(mq, nq)                                                            \
    _Pragma("unroll") for (int kk = 0; kk < 2; ++kk)                           \
    _Pragma("unroll") for (int mf = 0; mf < 4; ++mf)                           \
    _Pragma("unroll") for (int nf = 0; nf < 2; ++nf)                           \
        acc[(mq) * 4 + mf][(nq) * 2 + nf] =                                    \
            __builtin_amdgcn_mfma_f32_16x16x32_bf16(af[mf][kk], bf[nf][kk],    \
                acc[(mq) * 4 + mf][(nq) * 2 + nf], 0, 0, 0);

    f32x4 acc[8][4] = {};
    short8 af[4][2], bf[2][2];
    STG(ABASE(0), 0, stA0);
    STG(BBASE(0), 16384, stB_P1);
    STG(BBASE(0), 16384, stB_P3);
    STG(ABASE(0), 0, stA1);
    STG(ABASE(1), 32768, stA0);
    STG(BBASE(1), 49152, stB_P3);
    STG(ABASE(1), 32768, stA1);
    asm volatile("s_waitcnt vmcnt(6)" ::: "memory");   // tile0 complete
#pragma unroll 2
    for (int t = 0; t < NT; ++t) {
        const int curS = (t & 1) * 32768;
        const int nxtS = curS ^ 32768;
        // ---- P1: Q(0,0) ----
        __builtin_amdgcn_s_barrier();
        LD_A(0); LD_B(0);
        __builtin_amdgcn_s_setprio(1); QMM(0, 0); __builtin_amdgcn_s_setprio(0);
        if (t + 1 < NT) STG(BBASE(t + 1), nxtS + 16384, stB_P1);
        // ---- P2: Q(0,1) ----
        __builtin_amdgcn_s_barrier();
        LD_B(1);
        __builtin_amdgcn_s_setprio(1); QMM(0, 1); __builtin_amdgcn_s_setprio(0);
        if (t + 2 < NT) STG(ABASE(t + 2), curS, stA0);
        // ---- P3: Q(1,1) ----
        __builtin_amdgcn_s_barrier();
        LD_A(1);
        __builtin_amdgcn_s_setprio(1); QMM(1, 1); __builtin_amdgcn_s_setprio(0);
        if (t + 2 < NT) STG(BBASE(t + 2), curS + 16384, stB_P3);
        // ---- P4: Q(1,0) ----
        __builtin_amdgcn_s_barrier();
        LD_B(0);
        __builtin_amdgcn_s_setprio(1); QMM(1, 0); __builtin_amdgcn_s_setprio(0);
        if (t + 2 < NT) STG(ABASE(t + 2), curS, stA1);
        if (t < NT - 2) {
            asm volatile("s_waitcnt vmcnt(6)" ::: "memory");
        } else {
            asm volatile("s_waitcnt vmcnt(0)" ::: "memory");
        }
    }
#pragma unroll
    for (int mf = 0; mf < 8; ++mf) {
        const int grow = m0 + wm * 128 + mf * 16 + (lane >> 4) * 4;
#pragma unroll
        for (int nf = 0; nf < 4; ++nf) {
            const int gcol = n0 + wn * 64 + nf * 16 + lr;
            unsigned short* Cp = C + (size_t)grow * H_DIM + gcol;
#pragma unroll
            for (int j = 0; j < 4; ++j) Cp[(size_t)j * H_DIM] = f2bf(acc[mf][nf][j]);
        }
    }
#undef STG
#undef ABASE
#undef BBASE
#undef LD_A
#undef LD_B
#undef QMM
}

// ---------- rmsnorm + gelu (layer 1), one wave per 1024-wide row ----------
__global__ __launch_bounds__(256)
void norm_gelu(const unsigned short* __restrict__ Hp, const float* __restrict__ g,
               unsigned short* __restrict__ U) {
    const int row = blockIdx.x * 4 + (threadIdx.x >> 6);
    const int lane = threadIdx.x & 63;
    const unsigned short* rp = Hp + (size_t)row * H_DIM;
    short8 v0 = *(const short8*)(rp + lane * 8);
    short8 v1 = *(const short8*)(rp + 512 + lane * 8);
    float f[16];
#pragma unroll
    for (int j = 0; j < 8; ++j) {
        f[j] = bf2f((unsigned short)v0[j]);
        f[8 + j] = bf2f((unsigned short)v1[j]);
    }
    float s = 0.f;
#pragma unroll
    for (int j = 0; j < 16; ++j) s += f[j] * f[j];
#pragma unroll
    for (int o = 32; o > 0; o >>= 1) s += __shfl_xor(s, o);
    const float rinv = 1.f / sqrtf(s * (1.f / 1024.f) + 1e-6f);
    float4 ga0 = *(const float4*)(g + lane * 8);
    float4 ga1 = *(const float4*)(g + lane * 8 + 4);
    float4 gb0 = *(const float4*)(g + 512 + lane * 8);
    float4 gb1 = *(const float4*)(g + 512 + lane * 8 + 4);
    float gv[16] = {ga0.x, ga0.y, ga0.z, ga0.w, ga1.x, ga1.y, ga1.z, ga1.w,
                    gb0.x, gb0.y, gb0.z, gb0.w, gb1.x, gb1.y, gb1.z, gb1.w};
    short8 o0, o1;
#pragma unroll
    for (int j = 0; j < 8; ++j) {
        o0[j] = (short)f2bf(gelu_fast(f[j] * rinv * gv[j]));
        o1[j] = (short)f2bf(gelu_fast(f[8 + j] * rinv * gv[8 + j]));
    }
    unsigned short* up = U + (size_t)row * H_DIM;
    *(short8*)(up + lane * 8) = o0;
    *(short8*)(up + 512 + lane * 8) = o1;
}

// ---------- fused: rmsnorm + gelu + final 1024->10 GEMM (u never hits global) ----------
// Block = 16 rows: 4 waves norm+gelu 4 rows each -> Us LDS (padded stride 1032,
// 2-way conflicts = free); w3 staged once -> Ws; wave 0 runs 32 chained MFMAs.
__global__ __launch_bounds__(256)
void norm_gelu_out(const unsigned short* __restrict__ Hp, const float* __restrict__ g,
                   const unsigned short* __restrict__ w3q, float* __restrict__ out) {
    __shared__ unsigned short Us[16][1032];
    __shared__ unsigned short Ws[16][1032];
    const int tid = threadIdx.x;
    const int lane = tid & 63, wid = tid >> 6;
    const size_t r0 = (size_t)blockIdx.x * 16;
    for (int i = tid; i < 2048; i += 256) {           // stage w3: 16 x 128 granules
        const int r = i >> 7, cg = i & 127;
        *(short8*)&Ws[r][cg * 8] = *(const short8*)(w3q + (size_t)r * H_DIM + cg * 8);
    }
    float4 ga0 = *(const float4*)(g + lane * 8);
    float4 ga1 = *(const float4*)(g + lane * 8 + 4);
    float4 gb0 = *(const float4*)(g + 512 + lane * 8);
    float4 gb1 = *(const float4*)(g + 512 + lane * 8 + 4);
    float gv[16] = {ga0.x, ga0.y, ga0.z, ga0.w, ga1.x, ga1.y, ga1.z, ga1.w,
                    gb0.x, gb0.y, gb0.z, gb0.w, gb1.x, gb1.y, gb1.z, gb1.w};
#pragma unroll
    for (int rr = 0; rr < 4; ++rr) {
        const int row = wid * 4 + rr;
        const unsigned short* rp = Hp + (r0 + row) * H_DIM;
        short8 v0 = *(const short8*)(rp + lane * 8);
        short8 v1 = *(const short8*)(rp + 512 + lane * 8);
        float f[16];
#pragma unroll
        for (int j = 0; j < 8; ++j) {
            f[j] = bf2f((unsigned short)v0[j]);
            f[8 + j] = bf2f((unsigned short)v1[j]);
        }
        float s = 0.f;
#pragma unroll
        for (int j = 0; j < 16; ++j) s += f[j] * f[j];
#pragma unroll
        for (int o = 32; o > 0; o >>= 1) s += __shfl_xor(s, o);
        const float rinv = 1.f / sqrtf(s * (1.f / 1024.f) + 1e-6f);
        short8 o0, o1;
#pragma unroll
        for (int j = 0; j < 8; ++j) {
            o0[j] = (short)f2bf(gelu_fast(f[j] * rinv * gv[j]));
            o1[j] = (short)f2bf(gelu_fast(f[8 + j] * rinv * gv[8 + j]));
        }
        *(short8*)&Us[row][lane * 8] = o0;
        *(short8*)&Us[row][512 + lane * 8] = o1;
    }
    __syncthreads();
    if (wid == 0) {
        const int lr = lane & 15, lk = (lane >> 4) * 8;
        f32x4 acc = {};
#pragma unroll
        for (int ks = 0; ks < 32; ++ks) {
            short8 a = *(const short8*)&Us[lr][ks * 32 + lk];
            short8 b = *(const short8*)&Ws[lr][ks * 32 + lk];
            acc = __builtin_amdgcn_mfma_f32_16x16x32_bf16(a, b, acc, 0, 0, 0);
        }
        // C/D: col=lane&15 (= output o), row=(lane>>4)*4+j (= batch row)
        if (lr < OUT_DIM) {
#pragma unroll
            for (int j = 0; j < 4; ++j)
                out[(r0 + (lane >> 4) * 4 + j) * OUT_DIM + lr] = acc[j];
        }
    }
}

extern "C" void kernel_launch(void* const* d_in, const int* in_sizes, int n_in,
                              void* d_out, int out_size, void* d_ws, size_t ws_size,
                              hipStream_t stream) {
    (void)in_sizes; (void)n_in; (void)out_size;
    const float* x  = (const float*)d_in[0];
    const float* w1 = (const float*)d_in[1];
    const float* g1 = (const float*)d_in[2];
    const float* w2 = (const float*)d_in[3];
    const float* g2 = (const float*)d_in[4];
    const float* w3 = (const float*)d_in[5];
    float* out = (float*)d_out;

    uint8_t* ws = (uint8_t*)d_ws;
    double* sums = (double*)ws;
    size_t off = 256;
    unsigned short* w1q = (unsigned short*)(ws + off); off += (size_t)H_DIM * IN_PAD * 2;
    unsigned short* w2q = (unsigned short*)(ws + off); off += (size_t)H_DIM * H_DIM * 2;
    unsigned short* w3q = (unsigned short*)(ws + off); off += (size_t)OUT_PAD * H_DIM * 2;

    size_t rem = (ws_size > off) ? ws_size - off : 0;
    int R = B_TOTAL;
    while (R > 2048 && (size_t)2 * R * H_DIM * 2 > rem) R >>= 1;
    unsigned short* bufA = (unsigned short*)(ws + off);
    unsigned short* bufB = bufA + (size_t)R * H_DIM;

    hipMemsetAsync(sums, 0, 3 * sizeof(double), stream);
    absum3_kernel<<<dim3(128, 3), 256, 0, stream>>>(w1, w2, w3, sums);
    quant_all<<<dim3(4, 2064), 256, 0, stream>>>(w1, w2, w3, w1q, w2q, w3q, sums);

    const int nchunk = B_TOTAL / R;
    for (int c = 0; c < nchunk; ++c) {
        const float* xc = x + (size_t)c * R * IN_DIM;
        convert_pad<<<R * 112 / 256, 256, 0, stream>>>(xc, bufB);
        gemm_bt<IN_PAD><<<(R / 256) * 4, 512, 0, stream>>>(bufB, w1q, bufA);
        norm_gelu<<<R / 4, 256, 0, stream>>>(bufA, g1, bufB);
        gemm_bt<H_DIM><<<(R / 256) * 4, 512, 0, stream>>>(bufB, w2q, bufA);
        norm_gelu_out<<<R / 16, 256, 0, stream>>>(bufA, g2, w3q, out + (size_t)c * R * OUT_DIM);
    }
}